// Round 1
// baseline (1340.023 us; speedup 1.0000x reference)
//
#include <hip/hip_runtime.h>
#include <hip/hip_bf16.h>
#include <stdint.h>

// Problem: y[m][n] = sum_k x[m][k] * W[n][k],  W = (w_pos>0) - (w_neg>0) in {-1,0,1}
// M = 8*2048 = 16384, N = 4096, K = 4096. fp32 in/out; compute in bf16 MFMA
// (threshold 5.04 is a bf16-floor threshold; bf16 error ~1 max).

#define M_DIM 16384
#define N_DIM 4096
#define K_DIM 4096

#define BM 128
#define BN 128
#define BK 32

typedef unsigned short u16;
typedef __attribute__((ext_vector_type(8))) __bf16 bf16x8;
typedef __attribute__((ext_vector_type(4))) float f32x4;

__device__ __forceinline__ u16 f2bf(float f) {
    unsigned u = __float_as_uint(f);
    u += 0x7FFFu + ((u >> 16) & 1u);   // round-to-nearest-even
    return (u16)(u >> 16);
}

// ---- prologue: x fp32 -> bf16 ----
__global__ void cvt_x_kernel(const float4* __restrict__ x, uint2* __restrict__ xb, int n4) {
    int i = blockIdx.x * 256 + threadIdx.x;
    if (i >= n4) return;
    float4 v = x[i];
    uint2 r;
    r.x = (unsigned)f2bf(v.x) | ((unsigned)f2bf(v.y) << 16);
    r.y = (unsigned)f2bf(v.z) | ((unsigned)f2bf(v.w) << 16);
    xb[i] = r;
}

// ---- prologue: W = (wp>0) - (wn>0) as bf16 {-1,0,1} (exact) ----
__device__ __forceinline__ unsigned enc_w(float a, float b) {
    int s = (int)(a > 0.f) - (int)(b > 0.f);
    return s == 0 ? 0u : (s > 0 ? 0x3F80u : 0xBF80u);
}

__global__ void binarize_w_kernel(const float4* __restrict__ wp, const float4* __restrict__ wn,
                                  uint2* __restrict__ wb, int n4) {
    int i = blockIdx.x * 256 + threadIdx.x;
    if (i >= n4) return;
    float4 p = wp[i];
    float4 q = wn[i];
    uint2 r;
    r.x = enc_w(p.x, q.x) | (enc_w(p.y, q.y) << 16);
    r.y = enc_w(p.z, q.z) | (enc_w(p.w, q.w) << 16);
    wb[i] = r;
}

// ---- async global -> LDS, 16B per lane ----
__device__ __forceinline__ void gload_lds16(const u16* g, u16* l) {
    __builtin_amdgcn_global_load_lds(
        (const __attribute__((address_space(1))) void*)g,
        (__attribute__((address_space(3))) void*)l,
        16, 0, 0);
}

// ---- m97-structure GEMM: C[M][N] = A[M][K] * B[N][K]^T, bf16 in, fp32 out ----
// block = 256 threads (4 waves in 2x2), tile 128x128, BK=32.
// Each wave computes a 64x64 region = 4x4 tiles of 16x16 via mfma_f32_16x16x32_bf16.
__launch_bounds__(256)
__global__ void gemm_bin_kernel(const u16* __restrict__ A,   // [M][K] bf16 bits
                                const u16* __restrict__ B,   // [N][K] bf16 bits
                                float* __restrict__ C) {     // [M][N] fp32
    __shared__ u16 As[BM * BK];   // [row][k], rows of 64B — matches global_load_lds lane order
    __shared__ u16 Bs[BN * BK];

    const int t    = threadIdx.x;
    const int bm   = blockIdx.y * BM;
    const int bn   = blockIdx.x * BN;
    const int lane = t & 63;
    const int wid  = t >> 6;
    const int wm   = (wid >> 1) * 64;   // wave's M offset in tile
    const int wn   = (wid & 1) * 64;    // wave's N offset in tile
    const int l15  = lane & 15;
    const int quad = lane >> 4;

    // staging: thread t covers LDS bytes [t*16, t*16+16) => row t/4, k = (t&3)*8
    const int srow = t >> 2;          // 0..63
    const int skk  = (t & 3) * 8;     // 0,8,16,24
    const u16* gA0 = A + (size_t)(bm + srow) * K_DIM + skk;
    const u16* gA1 = gA0 + (size_t)64 * K_DIM;
    const u16* gB0 = B + (size_t)(bn + srow) * K_DIM + skk;
    const u16* gB1 = gB0 + (size_t)64 * K_DIM;
    u16* lA0 = As + t * 8;            // lane-contiguous: wave-uniform base + lane*16B
    u16* lA1 = As + 64 * BK + t * 8;  // rows 64..127
    u16* lB0 = Bs + t * 8;
    u16* lB1 = Bs + 64 * BK + t * 8;

    f32x4 acc[4][4];
#pragma unroll
    for (int i = 0; i < 4; i++)
#pragma unroll
        for (int j = 0; j < 4; j++) acc[i][j] = (f32x4){0.f, 0.f, 0.f, 0.f};

    for (int k0 = 0; k0 < K_DIM; k0 += BK) {
        gload_lds16(gA0 + k0, lA0);
        gload_lds16(gA1 + k0, lA1);
        gload_lds16(gB0 + k0, lB0);
        gload_lds16(gB1 + k0, lB1);
        __syncthreads();   // compiler emits s_waitcnt vmcnt(0) before s_barrier

        bf16x8 af[4], bf[4];
#pragma unroll
        for (int mi = 0; mi < 4; mi++)
            af[mi] = *(const bf16x8*)(As + (wm + mi * 16 + l15) * BK + quad * 8);
#pragma unroll
        for (int ni = 0; ni < 4; ni++)
            bf[ni] = *(const bf16x8*)(Bs + (wn + ni * 16 + l15) * BK + quad * 8);

#pragma unroll
        for (int mi = 0; mi < 4; mi++)
#pragma unroll
            for (int ni = 0; ni < 4; ni++)
                acc[mi][ni] = __builtin_amdgcn_mfma_f32_16x16x32_bf16(
                    af[mi], bf[ni], acc[mi][ni], 0, 0, 0);

        __syncthreads();   // protect LDS before next stage overwrites
    }

    // epilogue: C/D layout col=lane&15, row=quad*4+reg  [m89-verified]
#pragma unroll
    for (int mi = 0; mi < 4; mi++) {
#pragma unroll
        for (int ni = 0; ni < 4; ni++) {
            const int col = bn + wn + ni * 16 + l15;
#pragma unroll
            for (int r = 0; r < 4; r++) {
                const int row = bm + wm + mi * 16 + quad * 4 + r;
                C[(size_t)row * N_DIM + col] = acc[mi][ni][r];
            }
        }
    }
}

extern "C" void kernel_launch(void* const* d_in, const int* in_sizes, int n_in,
                              void* d_out, int out_size, void* d_ws, size_t ws_size,
                              hipStream_t stream) {
    const float* x  = (const float*)d_in[0];   // [16384][4096]
    const float* wp = (const float*)d_in[1];   // [4096][4096]
    const float* wn = (const float*)d_in[2];
    float* out = (float*)d_out;                // [16384][4096]

    // workspace layout: [0, 128MB) x_bf16 ; [128MB, 160MB) w_bf16
    u16* xb = (u16*)d_ws;
    u16* wb = (u16*)((char*)d_ws + (size_t)M_DIM * K_DIM * sizeof(u16));

    const int nx4 = M_DIM * K_DIM / 4;   // 16,777,216 float4s
    cvt_x_kernel<<<nx4 / 256, 256, 0, stream>>>((const float4*)x, (uint2*)xb, nx4);

    const int nw4 = N_DIM * K_DIM / 4;   // 4,194,304 float4s
    binarize_w_kernel<<<nw4 / 256, 256, 0, stream>>>(
        (const float4*)wp, (const float4*)wn, (uint2*)wb, nw4);

    dim3 grid(N_DIM / BN, M_DIM / BM);   // (32, 128)
    gemm_bin_kernel<<<grid, 256, 0, stream>>>(xb, wb, out);
}